// Round 5
// baseline (1715.390 us; speedup 1.0000x reference)
//
#include <hip/hip_runtime.h>

#define DFEAT 64
#define BSH 7
#define BN 128                    // nodes per bucket
#define NBUK 782                  // ceil(100000/128)
#define ASTRIDE 66                // padded LDS accumulator row stride
#define CPAD 16                   // global counter padding (64B line)
#define ETILE 8192

// ---- bucket histogram (LDS-reduced, padded global merge) ----
__global__ __launch_bounds__(512) void bhist_kernel(const int* __restrict__ dst,
                                                    int n_edges,
                                                    int* __restrict__ ghist) {
    __shared__ int lh[NBUK];
    int t = threadIdx.x;
    for (int i = t; i < NBUK; i += 512) lh[i] = 0;
    __syncthreads();
    int s0 = blockIdx.x * ETILE;
    int s1 = s0 + ETILE; if (s1 > n_edges) s1 = n_edges;
    for (int e = s0 + t; e < s1; e += 512)
        atomicAdd(&lh[dst[e] >> BSH], 1);
    __syncthreads();
    for (int i = t; i < NBUK; i += 512)
        if (lh[i]) atomicAdd(&ghist[i * CPAD], lh[i]);
}

// ---- exclusive scan of bucket counts (one block, 1024 threads) ----
__global__ __launch_bounds__(1024) void bscan_kernel(const int* __restrict__ ghist,
                                                     int* __restrict__ base,
                                                     int* __restrict__ gcur) {
    __shared__ int sdata[1024];
    int t = threadIdx.x;
    int v = (t < NBUK) ? ghist[t * CPAD] : 0;
    sdata[t] = v;
    __syncthreads();
    for (int off = 1; off < 1024; off <<= 1) {
        int x = (t >= off) ? sdata[t - off] : 0;
        __syncthreads();
        sdata[t] += x;
        __syncthreads();
    }
    int excl = sdata[t] - v;
    if (t <= NBUK) base[t] = excl;
    if (t < NBUK) gcur[t * CPAD] = excl;
}

// ---- partition: bucket-group edges; per-tile-bucket claiming; packed payload ----
__global__ __launch_bounds__(512) void partition_kernel(const int* __restrict__ src,
                                                        const int* __restrict__ dst,
                                                        int n_edges,
                                                        int* __restrict__ gcur,
                                                        int* __restrict__ tmp) {
    __shared__ int lhist[NBUK];
    __shared__ int lbase[NBUK];
    int t = threadIdx.x;
    for (int i = t; i < NBUK; i += 512) lhist[i] = 0;
    __syncthreads();
    int s0 = blockIdx.x * ETILE;
    int s1 = s0 + ETILE; if (s1 > n_edges) s1 = n_edges;
    for (int e = s0 + t; e < s1; e += 512)
        atomicAdd(&lhist[dst[e] >> BSH], 1);
    __syncthreads();
    for (int i = t; i < NBUK; i += 512) {
        int c = lhist[i];
        lbase[i] = c ? atomicAdd(&gcur[i * CPAD], c) : 0;
        lhist[i] = 0;                      // reuse as local cursor
    }
    __syncthreads();
    for (int e = s0 + t; e < s1; e += 512) {
        int d = dst[e];
        int bkt = d >> BSH;
        int ofs = atomicAdd(&lhist[bkt], 1);
        tmp[lbase[bkt] + ofs] = ((d & (BN - 1)) << 17) | src[e];
    }
}

// ---- fused gather + mean-aggregate: one block per bucket, LDS accumulators ----
__global__ __launch_bounds__(512, 4) void accum_kernel(
    const int* __restrict__ base, const int* __restrict__ tmp,
    const float* __restrict__ xin, float* __restrict__ agg, int n_nodes) {
    __shared__ float acc[BN * ASTRIDE];    // 33.8 KB
    __shared__ float cnt[BN];
    int t = threadIdx.x;
    for (int i = t; i < BN * ASTRIDE; i += 512) acc[i] = 0.f;
    if (t < BN) cnt[t] = 0.f;
    __syncthreads();

    int b = blockIdx.x;
    int start = base[b], end = base[b + 1];
    int w = t >> 6, lane = t & 63, g = lane >> 4, p = lane & 15;

    for (int cb = start + w * 64; cb < end; cb += 512) {
        int m = end - cb; if (m > 64) m = 64;
        int pk = tmp[cb + (lane < m ? lane : 0)];
        for (int i = 0; i < m; i += 16) {
#pragma unroll
            for (int k = 0; k < 4; ++k) {
                int n = i + 4 * k + g;
                int pkk = __shfl(pk, n < m ? n : 0);   // all lanes participate
                if (n < m) {
                    int s = pkk & 0x1FFFF;
                    int dlo = pkk >> 17;
                    float4 v = *(const float4*)&xin[(size_t)s * DFEAT + p * 4];
                    float* row = &acc[dlo * ASTRIDE + p * 4];
                    atomicAdd(row + 0, v.x);
                    atomicAdd(row + 1, v.y);
                    atomicAdd(row + 2, v.z);
                    atomicAdd(row + 3, v.w);
                    if (p == 0) atomicAdd(&cnt[dlo], 1.f);
                }
            }
        }
    }
    __syncthreads();

    int r = t >> 2, q = t & 3;                         // 128 rows x 4 quarters
    int node = b * BN + r;
    if (node < n_nodes) {
        float inv = 1.f / fmaxf(cnt[r], 1.f);
        const float* row = &acc[r * ASTRIDE + q * 16];
        float* o = &agg[(size_t)node * DFEAT + q * 16];
#pragma unroll
        for (int c = 0; c < 4; ++c) {
            float4 ov = make_float4(row[c * 4 + 0] * inv, row[c * 4 + 1] * inv,
                                    row[c * 4 + 2] * inv, row[c * 4 + 3] * inv);
            *(float4*)&o[c * 4] = ov;
        }
    }
}

// ---- linear: out = agg@Wl + xin@Wr + b, weights register-resident per lane ----
template <bool RELU>
__global__ __launch_bounds__(256) void linear_kernel(
    const float* __restrict__ agg, const float* __restrict__ xin,
    const float* __restrict__ Wl, const float* __restrict__ Wr,
    const float* __restrict__ bias, float* __restrict__ out, int n_nodes) {
    int lane = threadIdx.x & 63;
    int w = threadIdx.x >> 6;
    float wl[DFEAT], wr[DFEAT];
#pragma unroll
    for (int k = 0; k < DFEAT; ++k) {
        wl[k] = Wl[k * DFEAT + lane];
        wr[k] = Wr[k * DFEAT + lane];
    }
    float bj = bias[lane];
    int stride = gridDim.x * 4;
    for (int node = blockIdx.x * 4 + w; node < n_nodes; node += stride) {
        float a = agg[(size_t)node * DFEAT + lane];
        float xv = xin[(size_t)node * DFEAT + lane];
        float a0 = 0.f, a1 = 0.f, a2 = 0.f, a3 = 0.f;
#pragma unroll
        for (int k = 0; k < DFEAT; k += 4) {
            a0 += __shfl(a, k)     * wl[k]     + __shfl(xv, k)     * wr[k];
            a1 += __shfl(a, k + 1) * wl[k + 1] + __shfl(xv, k + 1) * wr[k + 1];
            a2 += __shfl(a, k + 2) * wl[k + 2] + __shfl(xv, k + 2) * wr[k + 2];
            a3 += __shfl(a, k + 3) * wl[k + 3] + __shfl(xv, k + 3) * wr[k + 3];
        }
        float r2 = bj + a0 + a1 + a2 + a3;
        if (RELU) r2 = fmaxf(r2, 0.f);
        out[(size_t)node * DFEAT + lane] = r2;
    }
}

extern "C" void kernel_launch(void* const* d_in, const int* in_sizes, int n_in,
                              void* d_out, int out_size, void* d_ws, size_t ws_size,
                              hipStream_t stream) {
    const float* x   = (const float*)d_in[0];
    const int*   ei  = (const int*)d_in[1];
    const float* Wl1 = (const float*)d_in[2];
    const float* Wr1 = (const float*)d_in[3];
    const float* b1  = (const float*)d_in[4];
    const float* Wl2 = (const float*)d_in[5];
    const float* Wr2 = (const float*)d_in[6];
    const float* b2  = (const float*)d_in[7];
    float* out = (float*)d_out;

    int n_nodes = in_sizes[0] / DFEAT;   // 100000
    int n_edges = in_sizes[1] / 2;       // 1600000
    const int* src  = ei;
    const int* dstv = ei + n_edges;

    auto align = [](size_t v) { return (v + 255) & ~(size_t)255; };
    char* ws = (char*)d_ws;
    int* ghist = (int*)ws;               ws += align((size_t)NBUK * CPAD * 4);  // 50KB
    int* gcur  = (int*)ws;               ws += align((size_t)NBUK * CPAD * 4);  // 50KB
    int* base  = (int*)ws;               ws += align(1024 * 4);
    float* A   = (float*)ws;             ws += align((size_t)n_nodes * DFEAT * 4);
    float* B   = (float*)ws;             ws += align((size_t)n_nodes * DFEAT * 4);
    int* tmp   = (int*)d_out;            // 6.4MB, dead until linear2 overwrites out

    hipMemsetAsync(ghist, 0, (size_t)NBUK * CPAD * 4, stream);

    int tb = (n_edges + ETILE - 1) / ETILE;   // 196
    bhist_kernel<<<tb, 512, 0, stream>>>(dstv, n_edges, ghist);
    bscan_kernel<<<1, 1024, 0, stream>>>(ghist, base, gcur);
    partition_kernel<<<tb, 512, 0, stream>>>(src, dstv, n_edges, gcur, tmp);

    // layer 1
    accum_kernel<<<NBUK, 512, 0, stream>>>(base, tmp, x, A, n_nodes);
    linear_kernel<true><<<1024, 256, 0, stream>>>(A, x, Wl1, Wr1, b1, B, n_nodes);
    // layer 2
    accum_kernel<<<NBUK, 512, 0, stream>>>(base, tmp, B, A, n_nodes);
    linear_kernel<false><<<1024, 256, 0, stream>>>(A, B, Wl2, Wr2, b2, out, n_nodes);
}

// Round 6
// 274.186 us; speedup vs baseline: 6.2563x; 6.2563x over previous
//
#include <hip/hip_runtime.h>

#define DFEAT 64
#define BSH 6
#define BN 64                     // nodes per bucket
#define NBUK 1563                 // ceil(100000/64)
#define CPAD 16                   // pad counters to one 64B line
#define ETILE 8192
#define PACKSH 17
#define SRCMASK 0x1FFFF

// ---- per-tile LDS bucket histogram + padded global merge ----
__global__ __launch_bounds__(512) void bhist_kernel(const int* __restrict__ dst,
                                                    int n_edges,
                                                    int* __restrict__ ghist) {
    __shared__ int lh[NBUK];
    int t = threadIdx.x;
    for (int i = t; i < NBUK; i += 512) lh[i] = 0;
    __syncthreads();
    int s0 = blockIdx.x * ETILE;
    int s1 = s0 + ETILE; if (s1 > n_edges) s1 = n_edges;
    for (int e = s0 + t; e < s1; e += 512)
        atomicAdd(&lh[dst[e] >> BSH], 1);
    __syncthreads();
    for (int i = t; i < NBUK; i += 512)
        if (lh[i]) atomicAdd(&ghist[i * CPAD], lh[i]);
}

// ---- scan 1563 bucket counts -> base[] (+ padded gcur[]) ----
__global__ __launch_bounds__(1024) void bscan_kernel(const int* __restrict__ ghist,
                                                     int* __restrict__ base,
                                                     int* __restrict__ gcur) {
    __shared__ int sdata[1024];
    int t = threadIdx.x;
    int i0 = 2 * t, i1 = 2 * t + 1;
    int v0 = (i0 < NBUK) ? ghist[i0 * CPAD] : 0;
    int v1 = (i1 < NBUK) ? ghist[i1 * CPAD] : 0;
    sdata[t] = v0 + v1;
    __syncthreads();
    for (int off = 1; off < 1024; off <<= 1) {
        int x = (t >= off) ? sdata[t - off] : 0;
        __syncthreads();
        sdata[t] += x;
        __syncthreads();
    }
    int excl = sdata[t] - (v0 + v1);
    if (i0 < NBUK) { base[i0] = excl;      gcur[i0 * CPAD] = excl; }
    if (i1 < NBUK) { base[i1] = excl + v0; gcur[i1 * CPAD] = excl + v0; }
    if (t == 1023) base[NBUK] = sdata[1023];
}

// ---- partition: per-tile LDS hist -> one padded claim per (tile,bucket) -> packed scatter ----
__global__ __launch_bounds__(512) void partition_kernel(const int* __restrict__ src,
                                                        const int* __restrict__ dst,
                                                        int n_edges,
                                                        int* __restrict__ gcur,
                                                        int* __restrict__ tmp) {
    __shared__ int lhist[NBUK];
    __shared__ int lbase[NBUK];
    int t = threadIdx.x;
    for (int i = t; i < NBUK; i += 512) lhist[i] = 0;
    __syncthreads();
    int s0 = blockIdx.x * ETILE;
    int s1 = s0 + ETILE; if (s1 > n_edges) s1 = n_edges;
    for (int e = s0 + t; e < s1; e += 512)
        atomicAdd(&lhist[dst[e] >> BSH], 1);
    __syncthreads();
    for (int i = t; i < NBUK; i += 512) {
        int c = lhist[i];
        lbase[i] = c ? atomicAdd(&gcur[i * CPAD], c) : 0;
        lhist[i] = 0;                      // reuse as local cursor
    }
    __syncthreads();
    for (int e = s0 + t; e < s1; e += 512) {
        int d = dst[e];
        int bkt = d >> BSH;
        int ofs = atomicAdd(&lhist[bkt], 1);
        tmp[lbase[bkt] + ofs] = ((d & (BN - 1)) << PACKSH) | src[e];
    }
}

// ---- per-bucket fine sort: builds row_ptr + col_src (LDS cursors, ~32 ops/counter) ----
__global__ __launch_bounds__(256) void bucket_sort_kernel(
    const int* __restrict__ base, const int* __restrict__ tmp,
    int* __restrict__ col_src, int* __restrict__ row_ptr,
    int n_nodes, int n_edges) {
    __shared__ int cnt[BN];
    __shared__ int cur[BN];
    int b = blockIdx.x, t = threadIdx.x;
    int gb = base[b], ge = base[b + 1];
    if (t < BN) cnt[t] = 0;
    __syncthreads();
    for (int e = gb + t; e < ge; e += 256)
        atomicAdd(&cnt[((unsigned)tmp[e]) >> PACKSH], 1);
    __syncthreads();
    if (t == 0) {                          // excl-scan of 64 counts, in place
        int run = 0;
        for (int i = 0; i < BN; ++i) { int c = cnt[i]; cnt[i] = run; run += c; }
    }
    __syncthreads();
    if (t < BN) {
        int node = (b << BSH) + t;
        if (node < n_nodes) row_ptr[node] = gb + cnt[t];
        cur[t] = gb + cnt[t];
    }
    if (t == 255 && b == (int)gridDim.x - 1) row_ptr[n_nodes] = n_edges;
    __syncthreads();
    for (int e = gb + t; e < ge; e += 256) {
        int pk = tmp[e];
        int pos = atomicAdd(&cur[((unsigned)pk) >> PACKSH], 1);
        col_src[pos] = pk & SRCMASK;
    }
}

// ---- fused SAGE layer (proven R3 kernel): gather-mean + two matvecs + bias (+ReLU) ----
template <bool RELU>
__global__ __launch_bounds__(512, 8) void sage_kernel(
    const int* __restrict__ row_ptr, const int* __restrict__ col_src,
    const float* __restrict__ xin, const float* __restrict__ Wl,
    const float* __restrict__ Wr, const float* __restrict__ b,
    float* __restrict__ out, int n_nodes) {
    __shared__ float sWl[DFEAT * DFEAT];
    __shared__ float sWr[DFEAT * DFEAT];
    __shared__ float sA[8][DFEAT];
    __shared__ float sX[8][DFEAT];

    {
        const float4* Wl4 = (const float4*)Wl;
        const float4* Wr4 = (const float4*)Wr;
        float4* sWl4 = (float4*)sWl;
        float4* sWr4 = (float4*)sWr;
        for (int i = threadIdx.x; i < DFEAT * DFEAT / 4; i += 512) {
            sWl4[i] = Wl4[i];
            sWr4[i] = Wr4[i];
        }
    }

    int w = threadIdx.x >> 6;
    int lane = threadIdx.x & 63;
    int g = lane >> 4;
    int p = lane & 15;
    int node = blockIdx.x * 8 + w;
    bool valid = node < n_nodes;
    int nc = valid ? node : (n_nodes - 1);

    float4 xrow = *(const float4*)&xin[(size_t)nc * DFEAT + p * 4];
    float bj = b[lane];

    int start = row_ptr[nc];
    int end = row_ptr[nc + 1];
    int deg = end - start;

    float4 acc4 = make_float4(0.f, 0.f, 0.f, 0.f);
    for (int base = start; base < end; base += 64) {
        int m = end - base;
        if (m > 64) m = 64;
        int sreg = col_src[base + (lane < m ? lane : 0)];
        for (int i = 0; i < m; i += 16) {
            int n0 = i + g, n1 = i + 4 + g, n2 = i + 8 + g, n3 = i + 12 + g;
            int s0 = __shfl(sreg, n0 < m ? n0 : 0);
            int s1 = __shfl(sreg, n1 < m ? n1 : 0);
            int s2 = __shfl(sreg, n2 < m ? n2 : 0);
            int s3 = __shfl(sreg, n3 < m ? n3 : 0);
            float4 v0 = *(const float4*)&xin[(size_t)s0 * DFEAT + p * 4];
            float4 v1 = *(const float4*)&xin[(size_t)s1 * DFEAT + p * 4];
            float4 v2 = *(const float4*)&xin[(size_t)s2 * DFEAT + p * 4];
            float4 v3 = *(const float4*)&xin[(size_t)s3 * DFEAT + p * 4];
            float f0 = (n0 < m) ? 1.f : 0.f;
            float f1 = (n1 < m) ? 1.f : 0.f;
            float f2 = (n2 < m) ? 1.f : 0.f;
            float f3 = (n3 < m) ? 1.f : 0.f;
            acc4.x += v0.x * f0 + v1.x * f1 + v2.x * f2 + v3.x * f3;
            acc4.y += v0.y * f0 + v1.y * f1 + v2.y * f2 + v3.y * f3;
            acc4.z += v0.z * f0 + v1.z * f1 + v2.z * f2 + v3.z * f3;
            acc4.w += v0.w * f0 + v1.w * f1 + v2.w * f2 + v3.w * f3;
        }
    }

    acc4.x += __shfl_xor(acc4.x, 16); acc4.x += __shfl_xor(acc4.x, 32);
    acc4.y += __shfl_xor(acc4.y, 16); acc4.y += __shfl_xor(acc4.y, 32);
    acc4.z += __shfl_xor(acc4.z, 16); acc4.z += __shfl_xor(acc4.z, 32);
    acc4.w += __shfl_xor(acc4.w, 16); acc4.w += __shfl_xor(acc4.w, 32);

    float invd = (deg > 0) ? 1.0f / (float)deg : 0.0f;
    if (g == 0) {
        float4 mv = make_float4(acc4.x * invd, acc4.y * invd,
                                acc4.z * invd, acc4.w * invd);
        *(float4*)&sA[w][p * 4] = mv;
    }
    if (g == 1) {
        *(float4*)&sX[w][p * 4] = xrow;
    }
    __syncthreads();

    float acc = bj;
#pragma unroll
    for (int k = 0; k < DFEAT; ++k) {
        acc += sA[w][k] * sWl[k * DFEAT + lane];
        acc += sX[w][k] * sWr[k * DFEAT + lane];
    }
    if (RELU) acc = fmaxf(acc, 0.0f);
    if (valid) out[(size_t)node * DFEAT + lane] = acc;
}

extern "C" void kernel_launch(void* const* d_in, const int* in_sizes, int n_in,
                              void* d_out, int out_size, void* d_ws, size_t ws_size,
                              hipStream_t stream) {
    const float* x   = (const float*)d_in[0];
    const int*   ei  = (const int*)d_in[1];
    const float* Wl1 = (const float*)d_in[2];
    const float* Wr1 = (const float*)d_in[3];
    const float* b1  = (const float*)d_in[4];
    const float* Wl2 = (const float*)d_in[5];
    const float* Wr2 = (const float*)d_in[6];
    const float* b2  = (const float*)d_in[7];
    float* out = (float*)d_out;

    int n_nodes = in_sizes[0] / DFEAT;   // 100000
    int n_edges = in_sizes[1] / 2;       // 1600000
    const int* src  = ei;
    const int* dstv = ei + n_edges;

    auto align = [](size_t v) { return (v + 255) & ~(size_t)255; };
    char* ws = (char*)d_ws;
    int* ghist   = (int*)ws;             ws += align((size_t)NBUK * CPAD * 4);   // 100KB
    int* gcur    = (int*)ws;             ws += align((size_t)NBUK * CPAD * 4);   // 100KB
    int* base    = (int*)ws;             ws += align((size_t)(NBUK + 1) * 4);
    int* row_ptr = (int*)ws;             ws += align(((size_t)n_nodes + 1) * 4);
    int* col_src = (int*)ws;             ws += align((size_t)n_edges * 4);       // 6.4MB
    float* h     = (float*)ws;                                                   // 25.6MB
    int* tmp     = (int*)d_out;          // 6.4MB, dead until sage<false> writes out

    hipMemsetAsync(ghist, 0, (size_t)NBUK * CPAD * 4, stream);

    int tb = (n_edges + ETILE - 1) / ETILE;   // 196
    bhist_kernel<<<tb, 512, 0, stream>>>(dstv, n_edges, ghist);
    bscan_kernel<<<1, 1024, 0, stream>>>(ghist, base, gcur);
    partition_kernel<<<tb, 512, 0, stream>>>(src, dstv, n_edges, gcur, tmp);
    bucket_sort_kernel<<<NBUK, 256, 0, stream>>>(base, tmp, col_src, row_ptr,
                                                 n_nodes, n_edges);

    int nb = (n_nodes + 7) / 8;
    sage_kernel<true><<<nb, 512, 0, stream>>>(row_ptr, col_src, x, Wl1, Wr1, b1, h, n_nodes);
    sage_kernel<false><<<nb, 512, 0, stream>>>(row_ptr, col_src, h, Wl2, Wr2, b2, out, n_nodes);
}

// Round 7
// 250.621 us; speedup vs baseline: 6.8445x; 1.0940x over previous
//
#include <hip/hip_runtime.h>

#define DFEAT 64
#define BSH 6
#define BN 64                     // nodes per bucket
#define NBUK 1563                 // ceil(100000/64)
#define CPAD 16                   // pad counters to one 64B line
#define ETILE 8192
#define PACKSH 17
#define SRCMASK 0x1FFFF

__device__ __forceinline__ unsigned bf16_rne(float v) {
    unsigned bits = __float_as_uint(v);
    return (bits + 0x7FFFu + ((bits >> 16) & 1u)) >> 16;
}

// ---- per-tile LDS bucket histogram + padded global merge ----
__global__ __launch_bounds__(512) void bhist_kernel(const int* __restrict__ dst,
                                                    int n_edges,
                                                    int* __restrict__ ghist) {
    __shared__ int lh[NBUK];
    int t = threadIdx.x;
    for (int i = t; i < NBUK; i += 512) lh[i] = 0;
    __syncthreads();
    int s0 = blockIdx.x * ETILE;
    int s1 = s0 + ETILE; if (s1 > n_edges) s1 = n_edges;
    for (int e = s0 + t; e < s1; e += 512)
        atomicAdd(&lh[dst[e] >> BSH], 1);
    __syncthreads();
    for (int i = t; i < NBUK; i += 512)
        if (lh[i]) atomicAdd(&ghist[i * CPAD], lh[i]);
}

// ---- scan 1563 bucket counts -> base[] (+ padded gcur[]) ----
__global__ __launch_bounds__(1024) void bscan_kernel(const int* __restrict__ ghist,
                                                     int* __restrict__ base,
                                                     int* __restrict__ gcur) {
    __shared__ int sdata[1024];
    int t = threadIdx.x;
    int i0 = 2 * t, i1 = 2 * t + 1;
    int v0 = (i0 < NBUK) ? ghist[i0 * CPAD] : 0;
    int v1 = (i1 < NBUK) ? ghist[i1 * CPAD] : 0;
    sdata[t] = v0 + v1;
    __syncthreads();
    for (int off = 1; off < 1024; off <<= 1) {
        int x = (t >= off) ? sdata[t - off] : 0;
        __syncthreads();
        sdata[t] += x;
        __syncthreads();
    }
    int excl = sdata[t] - (v0 + v1);
    if (i0 < NBUK) { base[i0] = excl;      gcur[i0 * CPAD] = excl; }
    if (i1 < NBUK) { base[i1] = excl + v0; gcur[i1 * CPAD] = excl + v0; }
    if (t == 1023) base[NBUK] = sdata[1023];
}

// ---- partition: per-tile LDS hist -> one padded claim per (tile,bucket) -> packed scatter ----
__global__ __launch_bounds__(512) void partition_kernel(const int* __restrict__ src,
                                                        const int* __restrict__ dst,
                                                        int n_edges,
                                                        int* __restrict__ gcur,
                                                        int* __restrict__ tmp) {
    __shared__ int lhist[NBUK];
    __shared__ int lbase[NBUK];
    int t = threadIdx.x;
    for (int i = t; i < NBUK; i += 512) lhist[i] = 0;
    __syncthreads();
    int s0 = blockIdx.x * ETILE;
    int s1 = s0 + ETILE; if (s1 > n_edges) s1 = n_edges;
    for (int e = s0 + t; e < s1; e += 512)
        atomicAdd(&lhist[dst[e] >> BSH], 1);
    __syncthreads();
    for (int i = t; i < NBUK; i += 512) {
        int c = lhist[i];
        lbase[i] = c ? atomicAdd(&gcur[i * CPAD], c) : 0;
        lhist[i] = 0;                      // reuse as local cursor
    }
    __syncthreads();
    for (int e = s0 + t; e < s1; e += 512) {
        int d = dst[e];
        int bkt = d >> BSH;
        int ofs = atomicAdd(&lhist[bkt], 1);
        tmp[lbase[bkt] + ofs] = ((d & (BN - 1)) << PACKSH) | src[e];
    }
}

// ---- per-bucket fine sort: builds row_ptr + col_src (stores src*128 byte offsets) ----
__global__ __launch_bounds__(256) void bucket_sort_kernel(
    const int* __restrict__ base, const int* __restrict__ tmp,
    int* __restrict__ col_src, int* __restrict__ row_ptr,
    int n_nodes, int n_edges) {
    __shared__ int cnt[BN];
    __shared__ int cur[BN];
    int b = blockIdx.x, t = threadIdx.x;
    int gb = base[b], ge = base[b + 1];
    if (t < BN) cnt[t] = 0;
    __syncthreads();
    for (int e = gb + t; e < ge; e += 256)
        atomicAdd(&cnt[((unsigned)tmp[e]) >> PACKSH], 1);
    __syncthreads();
    if (t == 0) {
        int run = 0;
        for (int i = 0; i < BN; ++i) { int c = cnt[i]; cnt[i] = run; run += c; }
    }
    __syncthreads();
    if (t < BN) {
        int node = (b << BSH) + t;
        if (node < n_nodes) row_ptr[node] = gb + cnt[t];
        cur[t] = gb + cnt[t];
    }
    if (t == 255 && b == (int)gridDim.x - 1) row_ptr[n_nodes] = n_edges;
    __syncthreads();
    for (int e = gb + t; e < ge; e += 256) {
        int pk = tmp[e];
        int pos = atomicAdd(&cur[((unsigned)pk) >> PACKSH], 1);
        col_src[pos] = (pk & SRCMASK) << 7;     // byte offset of 128B bf16 row
    }
}

// ---- fp32 -> bf16 row conversion (8 elems/thread) ----
__global__ __launch_bounds__(256) void cvt_kernel(const float* __restrict__ x,
                                                  unsigned short* __restrict__ xb,
                                                  int n8) {
    int i = blockIdx.x * 256 + threadIdx.x;
    if (i >= n8) return;
    const float4* xp = (const float4*)x;
    float4 a = xp[2 * i], c = xp[2 * i + 1];
    int4 o;
    o.x = bf16_rne(a.x) | (bf16_rne(a.y) << 16);
    o.y = bf16_rne(a.z) | (bf16_rne(a.w) << 16);
    o.z = bf16_rne(c.x) | (bf16_rne(c.y) << 16);
    o.w = bf16_rne(c.z) | (bf16_rne(c.w) << 16);
    ((int4*)xb)[i] = o;
}

// ---- gather-mean aggregation (bf16 rows): wave=node, 8 lanes/row, 8 rows/load ----
__global__ __launch_bounds__(512, 8) void agg_kernel(
    const int* __restrict__ row_ptr, const int* __restrict__ col_src,
    const unsigned short* __restrict__ xb, unsigned short* __restrict__ meanb,
    int n_nodes) {
    int w = threadIdx.x >> 6;
    int lane = threadIdx.x & 63;
    int g = lane >> 3;            // row-group 0..7
    int p = lane & 7;             // 16B slot within 128B row
    int node = blockIdx.x * 8 + w;
    if (node >= n_nodes) return;  // no barriers in this kernel

    int start = row_ptr[node];
    int end = row_ptr[node + 1];
    int deg = end - start;

    float acc[8] = {0.f, 0.f, 0.f, 0.f, 0.f, 0.f, 0.f, 0.f};
    const char* xbase = (const char*)xb + p * 16;

    for (int base = start; base < end; base += 64) {
        int m = end - base; if (m > 64) m = 64;
        int soff = col_src[base + (lane < m ? lane : 0)];
        for (int i = 0; i < m; i += 32) {
#pragma unroll
            for (int k = 0; k < 4; ++k) {
                if (i + 8 * k < m) {                       // wave-uniform
                    int n = i + 8 * k + g;
                    int off = __shfl(soff, n < m ? n : 0);
                    float f = (n < m) ? 1.0f : 0.0f;
                    int4 v = *(const int4*)(xbase + off);
                    acc[0] += f * __uint_as_float(((unsigned)v.x) << 16);
                    acc[1] += f * __uint_as_float(((unsigned)v.x) & 0xFFFF0000u);
                    acc[2] += f * __uint_as_float(((unsigned)v.y) << 16);
                    acc[3] += f * __uint_as_float(((unsigned)v.y) & 0xFFFF0000u);
                    acc[4] += f * __uint_as_float(((unsigned)v.z) << 16);
                    acc[5] += f * __uint_as_float(((unsigned)v.z) & 0xFFFF0000u);
                    acc[6] += f * __uint_as_float(((unsigned)v.w) << 16);
                    acc[7] += f * __uint_as_float(((unsigned)v.w) & 0xFFFF0000u);
                }
            }
        }
    }

#pragma unroll
    for (int d = 8; d < 64; d <<= 1) {
#pragma unroll
        for (int e = 0; e < 8; ++e) acc[e] += __shfl_xor(acc[e], d);
    }

    if (g == 0) {
        float inv = (deg > 0) ? 1.0f / (float)deg : 0.0f;
        unsigned u[8];
#pragma unroll
        for (int e = 0; e < 8; ++e) u[e] = bf16_rne(acc[e] * inv);
        int4 o;
        o.x = u[0] | (u[1] << 16);
        o.y = u[2] | (u[3] << 16);
        o.z = u[4] | (u[5] << 16);
        o.w = u[6] | (u[7] << 16);
        *(int4*)((char*)meanb + (size_t)node * 128 + p * 16) = o;
    }
}

// ---- linear: out = A@Wl + X@Wr + b ; weights in 128 VGPRs, rows staged fp32 in LDS ----
template <bool RELU, bool OUT_BF16>
__global__ __launch_bounds__(256) void linear_kernel(
    const unsigned short* __restrict__ Ab, const unsigned short* __restrict__ Xb,
    const float* __restrict__ Wl, const float* __restrict__ Wr,
    const float* __restrict__ bias, void* __restrict__ outp,
    int n_nodes, int ntiles) {
    __shared__ float sA[16][DFEAT];
    __shared__ float sX[16][DFEAT];
    int t = threadIdx.x;
    int lane = t & 63;
    int w = t >> 6;
    float wl[DFEAT], wr[DFEAT];
#pragma unroll
    for (int k = 0; k < DFEAT; ++k) {
        wl[k] = Wl[k * DFEAT + lane];
        wr[k] = Wr[k * DFEAT + lane];
    }
    float bj = bias[lane];

    for (int tile = blockIdx.x; tile < ntiles; tile += gridDim.x) {
        int node0 = tile * 16;
        __syncthreads();                                   // LDS reuse guard
        {
            int r = t & 127;                               // int4 slot in 16x64 bf16 tile
            int nd = r >> 3;
            int q = r & 7;
            const unsigned short* srcp = (t < 128) ? Ab : Xb;
            float (*dst)[DFEAT] = (t < 128) ? sA : sX;
            int gn = node0 + nd;
            if (gn < n_nodes) {
                int4 v = *(const int4*)(srcp + (size_t)gn * 64 + q * 8);
                float4 f0, f1;
                f0.x = __uint_as_float(((unsigned)v.x) << 16);
                f0.y = __uint_as_float(((unsigned)v.x) & 0xFFFF0000u);
                f0.z = __uint_as_float(((unsigned)v.y) << 16);
                f0.w = __uint_as_float(((unsigned)v.y) & 0xFFFF0000u);
                f1.x = __uint_as_float(((unsigned)v.z) << 16);
                f1.y = __uint_as_float(((unsigned)v.z) & 0xFFFF0000u);
                f1.z = __uint_as_float(((unsigned)v.w) << 16);
                f1.w = __uint_as_float(((unsigned)v.w) & 0xFFFF0000u);
                *(float4*)&dst[nd][q * 8] = f0;
                *(float4*)&dst[nd][q * 8 + 4] = f1;
            }
        }
        __syncthreads();
#pragma unroll
        for (int c = 0; c < 4; ++c) {
            int nd = w * 4 + c;
            int gn = node0 + nd;
            if (gn >= n_nodes) break;                      // wave-uniform
            float acc = bj;
#pragma unroll
            for (int k = 0; k < DFEAT; k += 4) {
                float4 a4 = *(const float4*)&sA[nd][k];    // broadcast reads
                float4 x4 = *(const float4*)&sX[nd][k];
                acc += a4.x * wl[k]     + x4.x * wr[k];
                acc += a4.y * wl[k + 1] + x4.y * wr[k + 1];
                acc += a4.z * wl[k + 2] + x4.z * wr[k + 2];
                acc += a4.w * wl[k + 3] + x4.w * wr[k + 3];
            }
            if (RELU) acc = fmaxf(acc, 0.0f);
            if (OUT_BF16) {
                unsigned r16 = bf16_rne(acc);
                unsigned other = __shfl_xor((int)r16, 1);
                if ((lane & 1) == 0) {
                    unsigned packed = r16 | (other << 16);
                    *(unsigned*)((unsigned short*)outp + (size_t)gn * 64 + lane) = packed;
                }
            } else {
                ((float*)outp)[(size_t)gn * DFEAT + lane] = acc;
            }
        }
    }
}

extern "C" void kernel_launch(void* const* d_in, const int* in_sizes, int n_in,
                              void* d_out, int out_size, void* d_ws, size_t ws_size,
                              hipStream_t stream) {
    const float* x   = (const float*)d_in[0];
    const int*   ei  = (const int*)d_in[1];
    const float* Wl1 = (const float*)d_in[2];
    const float* Wr1 = (const float*)d_in[3];
    const float* b1  = (const float*)d_in[4];
    const float* Wl2 = (const float*)d_in[5];
    const float* Wr2 = (const float*)d_in[6];
    const float* b2  = (const float*)d_in[7];
    float* out = (float*)d_out;

    int n_nodes = in_sizes[0] / DFEAT;   // 100000
    int n_edges = in_sizes[1] / 2;       // 1600000
    const int* src  = ei;
    const int* dstv = ei + n_edges;

    auto align = [](size_t v) { return (v + 255) & ~(size_t)255; };
    char* ws = (char*)d_ws;
    int* ghist   = (int*)ws;             ws += align((size_t)NBUK * CPAD * 4);
    int* gcur    = (int*)ws;             ws += align((size_t)NBUK * CPAD * 4);
    int* base    = (int*)ws;             ws += align((size_t)(NBUK + 1) * 4);
    int* row_ptr = (int*)ws;             ws += align(((size_t)n_nodes + 1) * 4);
    int* col_src = (int*)ws;             ws += align((size_t)n_edges * 4);       // 6.4MB
    unsigned short* xb    = (unsigned short*)ws; ws += align((size_t)n_nodes * DFEAT * 2);
    unsigned short* hb    = (unsigned short*)ws; ws += align((size_t)n_nodes * DFEAT * 2);
    unsigned short* meanb = (unsigned short*)ws; ws += align((size_t)n_nodes * DFEAT * 2);
    int* tmp     = (int*)d_out;          // 6.4MB, dead until linear2 writes out

    hipMemsetAsync(ghist, 0, (size_t)NBUK * CPAD * 4, stream);

    int tb = (n_edges + ETILE - 1) / ETILE;   // 196
    bhist_kernel<<<tb, 512, 0, stream>>>(dstv, n_edges, ghist);
    bscan_kernel<<<1, 1024, 0, stream>>>(ghist, base, gcur);
    partition_kernel<<<tb, 512, 0, stream>>>(src, dstv, n_edges, gcur, tmp);
    bucket_sort_kernel<<<NBUK, 256, 0, stream>>>(base, tmp, col_src, row_ptr,
                                                 n_nodes, n_edges);

    int n8 = n_nodes * DFEAT / 8;
    cvt_kernel<<<(n8 + 255) / 256, 256, 0, stream>>>(x, xb, n8);

    int ntiles = (n_nodes + 15) / 16;    // 6250
    int nb = (n_nodes + 7) / 8;          // 12500

    agg_kernel<<<nb, 512, 0, stream>>>(row_ptr, col_src, xb, meanb, n_nodes);
    linear_kernel<true, true><<<512, 256, 0, stream>>>(meanb, xb, Wl1, Wr1, b1,
                                                       hb, n_nodes, ntiles);
    agg_kernel<<<nb, 512, 0, stream>>>(row_ptr, col_src, hb, meanb, n_nodes);
    linear_kernel<false, false><<<512, 256, 0, stream>>>(meanb, hb, Wl2, Wr2, b2,
                                                         out, n_nodes, ntiles);
}

// Round 8
// 199.402 us; speedup vs baseline: 8.6027x; 1.2569x over previous
//
#include <hip/hip_runtime.h>

#define DFEAT 64
#define BSH 6
#define BN 64                     // nodes per bucket
#define NBUK 1563                 // ceil(100000/64)
#define CPAD 16                   // pad counters to one 64B line
#define ETILE 8192
#define PACKSH 17
#define SRCMASK 0x1FFFF

typedef __bf16 bf16x8 __attribute__((ext_vector_type(8)));
typedef float f32x4 __attribute__((ext_vector_type(4)));

__device__ __forceinline__ unsigned bf16_rne(float v) {
    unsigned bits = __float_as_uint(v);
    return (bits + 0x7FFFu + ((bits >> 16) & 1u)) >> 16;
}

// ---- per-tile LDS bucket histogram + padded global merge ----
__global__ __launch_bounds__(512) void bhist_kernel(const int* __restrict__ dst,
                                                    int n_edges,
                                                    int* __restrict__ ghist) {
    __shared__ int lh[NBUK];
    int t = threadIdx.x;
    for (int i = t; i < NBUK; i += 512) lh[i] = 0;
    __syncthreads();
    int s0 = blockIdx.x * ETILE;
    int s1 = s0 + ETILE; if (s1 > n_edges) s1 = n_edges;
    for (int e = s0 + t; e < s1; e += 512)
        atomicAdd(&lh[dst[e] >> BSH], 1);
    __syncthreads();
    for (int i = t; i < NBUK; i += 512)
        if (lh[i]) atomicAdd(&ghist[i * CPAD], lh[i]);
}

// ---- scan 1563 bucket counts -> base[] (+ padded gcur[]) ----
__global__ __launch_bounds__(1024) void bscan_kernel(const int* __restrict__ ghist,
                                                     int* __restrict__ base,
                                                     int* __restrict__ gcur) {
    __shared__ int sdata[1024];
    int t = threadIdx.x;
    int i0 = 2 * t, i1 = 2 * t + 1;
    int v0 = (i0 < NBUK) ? ghist[i0 * CPAD] : 0;
    int v1 = (i1 < NBUK) ? ghist[i1 * CPAD] : 0;
    sdata[t] = v0 + v1;
    __syncthreads();
    for (int off = 1; off < 1024; off <<= 1) {
        int x = (t >= off) ? sdata[t - off] : 0;
        __syncthreads();
        sdata[t] += x;
        __syncthreads();
    }
    int excl = sdata[t] - (v0 + v1);
    if (i0 < NBUK) { base[i0] = excl;      gcur[i0 * CPAD] = excl; }
    if (i1 < NBUK) { base[i1] = excl + v0; gcur[i1 * CPAD] = excl + v0; }
    if (t == 1023) base[NBUK] = sdata[1023];
}

// ---- partition: per-tile LDS hist -> one padded claim per (tile,bucket) -> packed scatter ----
__global__ __launch_bounds__(512) void partition_kernel(const int* __restrict__ src,
                                                        const int* __restrict__ dst,
                                                        int n_edges,
                                                        int* __restrict__ gcur,
                                                        int* __restrict__ tmp) {
    __shared__ int lhist[NBUK];
    __shared__ int lbase[NBUK];
    int t = threadIdx.x;
    for (int i = t; i < NBUK; i += 512) lhist[i] = 0;
    __syncthreads();
    int s0 = blockIdx.x * ETILE;
    int s1 = s0 + ETILE; if (s1 > n_edges) s1 = n_edges;
    for (int e = s0 + t; e < s1; e += 512)
        atomicAdd(&lhist[dst[e] >> BSH], 1);
    __syncthreads();
    for (int i = t; i < NBUK; i += 512) {
        int c = lhist[i];
        lbase[i] = c ? atomicAdd(&gcur[i * CPAD], c) : 0;
        lhist[i] = 0;                      // reuse as local cursor
    }
    __syncthreads();
    for (int e = s0 + t; e < s1; e += 512) {
        int d = dst[e];
        int bkt = d >> BSH;
        int ofs = atomicAdd(&lhist[bkt], 1);
        tmp[lbase[bkt] + ofs] = ((d & (BN - 1)) << PACKSH) | src[e];
    }
}

// ---- per-bucket fine sort: builds row_ptr + col_src (stores src*128 byte offsets) ----
__global__ __launch_bounds__(256) void bucket_sort_kernel(
    const int* __restrict__ base, const int* __restrict__ tmp,
    int* __restrict__ col_src, int* __restrict__ row_ptr,
    int n_nodes, int n_edges) {
    __shared__ int cnt[BN];
    __shared__ int cur[BN];
    int b = blockIdx.x, t = threadIdx.x;
    int gb = base[b], ge = base[b + 1];
    if (t < BN) cnt[t] = 0;
    __syncthreads();
    for (int e = gb + t; e < ge; e += 256)
        atomicAdd(&cnt[((unsigned)tmp[e]) >> PACKSH], 1);
    __syncthreads();
    if (t == 0) {
        int run = 0;
        for (int i = 0; i < BN; ++i) { int c = cnt[i]; cnt[i] = run; run += c; }
    }
    __syncthreads();
    if (t < BN) {
        int node = (b << BSH) + t;
        if (node < n_nodes) row_ptr[node] = gb + cnt[t];
        cur[t] = gb + cnt[t];
    }
    if (t == 255 && b == (int)gridDim.x - 1) row_ptr[n_nodes] = n_edges;
    __syncthreads();
    for (int e = gb + t; e < ge; e += 256) {
        int pk = tmp[e];
        int pos = atomicAdd(&cur[((unsigned)pk) >> PACKSH], 1);
        col_src[pos] = (pk & SRCMASK) << 7;     // byte offset of 128B bf16 row
    }
}

// ---- fp32 -> bf16 row conversion (8 elems/thread) ----
__global__ __launch_bounds__(256) void cvt_kernel(const float* __restrict__ x,
                                                  unsigned short* __restrict__ xb,
                                                  int n8) {
    int i = blockIdx.x * 256 + threadIdx.x;
    if (i >= n8) return;
    const float4* xp = (const float4*)x;
    float4 a = xp[2 * i], c = xp[2 * i + 1];
    int4 o;
    o.x = bf16_rne(a.x) | (bf16_rne(a.y) << 16);
    o.y = bf16_rne(a.z) | (bf16_rne(a.w) << 16);
    o.z = bf16_rne(c.x) | (bf16_rne(c.y) << 16);
    o.w = bf16_rne(c.z) | (bf16_rne(c.w) << 16);
    ((int4*)xb)[i] = o;
}

// ---- pack weights (fp32 64x64 k-major) into MFMA B-fragments, hi/lo bf16 split ----
// frag index: ((((layer*2+gemm)*2+part)*2+chunk)*4+ct)*64 + lane ; 16B per frag
__global__ __launch_bounds__(256) void wpack_kernel(
    const float* __restrict__ Wl1, const float* __restrict__ Wr1,
    const float* __restrict__ Wl2, const float* __restrict__ Wr2,
    unsigned short* __restrict__ wpack) {
    int u = blockIdx.x * 256 + threadIdx.x;   // 2048 units
    if (u >= 2048) return;
    int l = u & 63;
    int ct = (u >> 6) & 3;
    int chunk = (u >> 8) & 1;
    int gemm = (u >> 9) & 1;
    int layer = (u >> 10) & 1;
    const float* W = layer ? (gemm ? Wr2 : Wl2) : (gemm ? Wr1 : Wl1);
    int col = ct * 16 + (l & 15);
    int k0 = chunk * 32 + (l >> 4) * 8;
    unsigned hi[8], lo[8];
#pragma unroll
    for (int j = 0; j < 8; ++j) {
        float w = W[(k0 + j) * DFEAT + col];
        unsigned h = bf16_rne(w);
        float whi = __uint_as_float(h << 16);
        lo[j] = bf16_rne(w - whi);
        hi[j] = h;
    }
    size_t fh = ((((size_t)(layer * 2 + gemm) * 2 + 0) * 2 + chunk) * 4 + ct) * 64 + l;
    size_t fl = ((((size_t)(layer * 2 + gemm) * 2 + 1) * 2 + chunk) * 4 + ct) * 64 + l;
    int4 vh, vl;
    vh.x = hi[0] | (hi[1] << 16); vh.y = hi[2] | (hi[3] << 16);
    vh.z = hi[4] | (hi[5] << 16); vh.w = hi[6] | (hi[7] << 16);
    vl.x = lo[0] | (lo[1] << 16); vl.y = lo[2] | (lo[3] << 16);
    vl.z = lo[4] | (lo[5] << 16); vl.w = lo[6] | (lo[7] << 16);
    ((int4*)wpack)[fh] = vh;
    ((int4*)wpack)[fl] = vl;
}

// ---- gather-mean aggregation (bf16 rows): wave=node, 8 lanes/row, 8 rows/load ----
__global__ __launch_bounds__(512, 8) void agg_kernel(
    const int* __restrict__ row_ptr, const int* __restrict__ col_src,
    const unsigned short* __restrict__ xb, unsigned short* __restrict__ meanb,
    int n_nodes) {
    int w = threadIdx.x >> 6;
    int lane = threadIdx.x & 63;
    int g = lane >> 3;            // row-group 0..7
    int p = lane & 7;             // 16B slot within 128B row
    int node = blockIdx.x * 8 + w;
    if (node >= n_nodes) return;  // no barriers in this kernel

    int start = row_ptr[node];
    int end = row_ptr[node + 1];
    int deg = end - start;

    float acc[8] = {0.f, 0.f, 0.f, 0.f, 0.f, 0.f, 0.f, 0.f};
    const char* xbase = (const char*)xb + p * 16;

    for (int base = start; base < end; base += 64) {
        int m = end - base; if (m > 64) m = 64;
        int soff = col_src[base + (lane < m ? lane : 0)];
        for (int i = 0; i < m; i += 32) {
#pragma unroll
            for (int k = 0; k < 4; ++k) {
                if (i + 8 * k < m) {                       // wave-uniform
                    int n = i + 8 * k + g;
                    int off = __shfl(soff, n < m ? n : 0);
                    float f = (n < m) ? 1.0f : 0.0f;
                    int4 v = *(const int4*)(xbase + off);
                    acc[0] += f * __uint_as_float(((unsigned)v.x) << 16);
                    acc[1] += f * __uint_as_float(((unsigned)v.x) & 0xFFFF0000u);
                    acc[2] += f * __uint_as_float(((unsigned)v.y) << 16);
                    acc[3] += f * __uint_as_float(((unsigned)v.y) & 0xFFFF0000u);
                    acc[4] += f * __uint_as_float(((unsigned)v.z) << 16);
                    acc[5] += f * __uint_as_float(((unsigned)v.z) & 0xFFFF0000u);
                    acc[6] += f * __uint_as_float(((unsigned)v.w) << 16);
                    acc[7] += f * __uint_as_float(((unsigned)v.w) & 0xFFFF0000u);
                }
            }
        }
    }

#pragma unroll
    for (int d = 8; d < 64; d <<= 1) {
#pragma unroll
        for (int e = 0; e < 8; ++e) acc[e] += __shfl_xor(acc[e], d);
    }

    if (g == 0) {
        float inv = (deg > 0) ? 1.0f / (float)deg : 0.0f;
        unsigned u[8];
#pragma unroll
        for (int e = 0; e < 8; ++e) u[e] = bf16_rne(acc[e] * inv);
        int4 o;
        o.x = u[0] | (u[1] << 16);
        o.y = u[2] | (u[3] << 16);
        o.z = u[4] | (u[5] << 16);
        o.w = u[6] | (u[7] << 16);
        *(int4*)((char*)meanb + (size_t)node * 128 + p * 16) = o;
    }
}

// ---- MFMA linear: out[16n x 64] = [A|X] @ [Wl;Wr] + b ; one wave per 16-node tile ----
template <bool RELU, bool OUT_BF16>
__global__ __launch_bounds__(256) void linear_kernel(
    const unsigned short* __restrict__ Ab, const unsigned short* __restrict__ Xb,
    const unsigned short* __restrict__ wpack,   // layer-offset applied by caller
    const float* __restrict__ bias, void* __restrict__ outp,
    int n_nodes, int ntiles) {
    int wave = (blockIdx.x * 256 + threadIdx.x) >> 6;
    if (wave >= ntiles) return;
    int l = threadIdx.x & 63;
    int row16 = l & 15;
    int kq = l >> 4;
    int node0 = wave * 16;

    int arow = node0 + row16;
    if (arow >= n_nodes) arow = n_nodes - 1;
    const char* ap = (const char*)Ab + (size_t)arow * 128 + kq * 16;
    const char* xp = (const char*)Xb + (size_t)arow * 128 + kq * 16;
    bf16x8 aA0 = *(const bf16x8*)ap;
    bf16x8 aA1 = *(const bf16x8*)(ap + 64);
    bf16x8 aX0 = *(const bf16x8*)xp;
    bf16x8 aX1 = *(const bf16x8*)(xp + 64);

    const bf16x8* wp = (const bf16x8*)wpack;
#pragma unroll
    for (int ct = 0; ct < 4; ++ct) {
        float bcol = bias[ct * 16 + row16];
        f32x4 acc = {bcol, bcol, bcol, bcol};
        // frag idx: ((gemm*2+part)*2+chunk)*256 + ct*64 + l
        bf16x8 b000 = wp[0 * 256 + ct * 64 + l];   // A, hi, c0
        bf16x8 b001 = wp[1 * 256 + ct * 64 + l];   // A, hi, c1
        bf16x8 b010 = wp[2 * 256 + ct * 64 + l];   // A, lo, c0
        bf16x8 b011 = wp[3 * 256 + ct * 64 + l];   // A, lo, c1
        bf16x8 b100 = wp[4 * 256 + ct * 64 + l];   // X, hi, c0
        bf16x8 b101 = wp[5 * 256 + ct * 64 + l];   // X, hi, c1
        bf16x8 b110 = wp[6 * 256 + ct * 64 + l];   // X, lo, c0
        bf16x8 b111 = wp[7 * 256 + ct * 64 + l];   // X, lo, c1
        acc = __builtin_amdgcn_mfma_f32_16x16x32_bf16(aA0, b000, acc, 0, 0, 0);
        acc = __builtin_amdgcn_mfma_f32_16x16x32_bf16(aA1, b001, acc, 0, 0, 0);
        acc = __builtin_amdgcn_mfma_f32_16x16x32_bf16(aA0, b010, acc, 0, 0, 0);
        acc = __builtin_amdgcn_mfma_f32_16x16x32_bf16(aA1, b011, acc, 0, 0, 0);
        acc = __builtin_amdgcn_mfma_f32_16x16x32_bf16(aX0, b100, acc, 0, 0, 0);
        acc = __builtin_amdgcn_mfma_f32_16x16x32_bf16(aX1, b101, acc, 0, 0, 0);
        acc = __builtin_amdgcn_mfma_f32_16x16x32_bf16(aX0, b110, acc, 0, 0, 0);
        acc = __builtin_amdgcn_mfma_f32_16x16x32_bf16(aX1, b111, acc, 0, 0, 0);
#pragma unroll
        for (int reg = 0; reg < 4; ++reg) {
            int row = kq * 4 + reg;                // C/D: row=(lane>>4)*4+reg
            int gn = node0 + row;
            if (gn < n_nodes) {
                float v = acc[reg];
                if (RELU) v = fmaxf(v, 0.0f);
                if (OUT_BF16) {
                    ((unsigned short*)outp)[(size_t)gn * DFEAT + ct * 16 + row16] =
                        (unsigned short)bf16_rne(v);
                } else {
                    ((float*)outp)[(size_t)gn * DFEAT + ct * 16 + row16] = v;
                }
            }
        }
    }
}

extern "C" void kernel_launch(void* const* d_in, const int* in_sizes, int n_in,
                              void* d_out, int out_size, void* d_ws, size_t ws_size,
                              hipStream_t stream) {
    const float* x   = (const float*)d_in[0];
    const int*   ei  = (const int*)d_in[1];
    const float* Wl1 = (const float*)d_in[2];
    const float* Wr1 = (const float*)d_in[3];
    const float* b1  = (const float*)d_in[4];
    const float* Wl2 = (const float*)d_in[5];
    const float* Wr2 = (const float*)d_in[6];
    const float* b2  = (const float*)d_in[7];
    float* out = (float*)d_out;

    int n_nodes = in_sizes[0] / DFEAT;   // 100000
    int n_edges = in_sizes[1] / 2;       // 1600000
    const int* src  = ei;
    const int* dstv = ei + n_edges;

    auto align = [](size_t v) { return (v + 255) & ~(size_t)255; };
    char* ws = (char*)d_ws;
    int* ghist   = (int*)ws;             ws += align((size_t)NBUK * CPAD * 4);
    int* gcur    = (int*)ws;             ws += align((size_t)NBUK * CPAD * 4);
    int* base    = (int*)ws;             ws += align((size_t)(NBUK + 1) * 4);
    int* row_ptr = (int*)ws;             ws += align(((size_t)n_nodes + 1) * 4);
    int* col_src = (int*)ws;             ws += align((size_t)n_edges * 4);       // 6.4MB
    unsigned short* xb    = (unsigned short*)ws; ws += align((size_t)n_nodes * DFEAT * 2);
    unsigned short* hb    = (unsigned short*)ws; ws += align((size_t)n_nodes * DFEAT * 2);
    unsigned short* meanb = (unsigned short*)ws; ws += align((size_t)n_nodes * DFEAT * 2);
    unsigned short* wpack = (unsigned short*)ws; ws += align((size_t)2 * 2 * 2 * 2 * 4 * 64 * 8 * 2);
    int* tmp     = (int*)d_out;          // 6.4MB, dead until linear2 writes out

    hipMemsetAsync(ghist, 0, (size_t)NBUK * CPAD * 4, stream);

    int tb = (n_edges + ETILE - 1) / ETILE;   // 196
    bhist_kernel<<<tb, 512, 0, stream>>>(dstv, n_edges, ghist);
    bscan_kernel<<<1, 1024, 0, stream>>>(ghist, base, gcur);
    partition_kernel<<<tb, 512, 0, stream>>>(src, dstv, n_edges, gcur, tmp);
    bucket_sort_kernel<<<NBUK, 256, 0, stream>>>(base, tmp, col_src, row_ptr,
                                                 n_nodes, n_edges);

    int n8 = n_nodes * DFEAT / 8;
    cvt_kernel<<<(n8 + 255) / 256, 256, 0, stream>>>(x, xb, n8);
    wpack_kernel<<<8, 256, 0, stream>>>(Wl1, Wr1, Wl2, Wr2, wpack);

    int ntiles = (n_nodes + 15) / 16;    // 6250
    int nb = (n_nodes + 7) / 8;          // 12500
    int lb = (ntiles + 3) / 4;           // 1563 blocks (4 waves each)

    agg_kernel<<<nb, 512, 0, stream>>>(row_ptr, col_src, xb, meanb, n_nodes);
    linear_kernel<true, true><<<lb, 256, 0, stream>>>(meanb, xb, wpack, b1,
                                                      hb, n_nodes, ntiles);
    agg_kernel<<<nb, 512, 0, stream>>>(row_ptr, col_src, hb, meanb, n_nodes);
    linear_kernel<false, false><<<lb, 256, 0, stream>>>(meanb, hb, wpack + 2048 * 8,
                                                        b2, out, n_nodes, ntiles);
}